// Round 3
// baseline (473.355 us; speedup 1.0000x reference)
//
#include <hip/hip_runtime.h>

#define TSTEPS 128
#define NIN 24
#define HD 128
#define BT 16
#define NBLK 128     // 2048 / BT
#define NTH 512

// LDS geometry (units: _Float16 elements)
#define RS    136               // h-panel row stride (272 B: 16B-aligned)
#define SLOT  (BT*RS)           // 2176
#define XS    40                // x row stride (cols 0..23 x, col 24 = 1.0 bias hook, rest 0)
#define XTS   (BT*XS)           // 640 per timestep
#define XCH   4                 // steps per x chunk
#define XBUF  (XCH*XTS)         // 2560

#define WIH0_OFF 0                      // frag table: 4 tI * 8 wv * 64 ln * 8 f16 = 16384
#define H1_OFF   16384                  // 2 slots
#define H2_OFF   (H1_OFF + 2*SLOT)     // 20736
#define XB_OFF   (H2_OFF + 2*SLOT)     // 25088
#define SM_SIZE  (XB_OFF + 2*XBUF)     // 30208 f16 = 60416 B

typedef _Float16 half8  __attribute__((ext_vector_type(8)));
typedef _Float16 half4v __attribute__((ext_vector_type(4)));
typedef float    floatx4 __attribute__((ext_vector_type(4)));

__device__ __forceinline__ float sigf(float x) {
    return __builtin_amdgcn_rcpf(1.0f + __expf(-x));
}
__device__ __forceinline__ float tanh_f(float x) {
    return 1.0f - 2.0f * __builtin_amdgcn_rcpf(1.0f + __expf(2.0f * x));
}

__device__ __forceinline__ half8 ldw8(const float* p) {
    const float4* q = (const float4*)p;
    float4 a = q[0], b = q[1];
    half8 r;
    r[0] = (_Float16)a.x; r[1] = (_Float16)a.y; r[2] = (_Float16)a.z; r[3] = (_Float16)a.w;
    r[4] = (_Float16)b.x; r[5] = (_Float16)b.y; r[6] = (_Float16)b.z; r[7] = (_Float16)b.w;
    return r;
}

__global__ __launch_bounds__(NTH, 2)
void lstm2_il(const float* __restrict__ x,
              const float* __restrict__ Wih0, const float* __restrict__ Whh0,
              const float* __restrict__ bih0, const float* __restrict__ bhh0,
              const float* __restrict__ Wih1, const float* __restrict__ Whh1,
              const float* __restrict__ bih1, const float* __restrict__ bhh1,
              const float* __restrict__ Wfc,  const float* __restrict__ bfc,
              float* __restrict__ out)
{
    __shared__ __align__(16) _Float16 SM[SM_SIZE];

    const int tid = threadIdx.x;
    const int blk = blockIdx.x;
    const int wv  = tid >> 6;
    const int ln  = tid & 63;
    const int qd  = ln >> 4;
    const int nn  = ln & 15;
    const int b0  = blk * BT;
    const int jc  = wv * 16 + nn;       // this lane's h/gate column

    const half8 z8 = {0, 0, 0, 0, 0, 0, 0, 0};

    // ---- zero all LDS (h slots = initial h=0; x pad cols stay 0) ----
    for (int i = tid * 8; i < SM_SIZE; i += NTH * 8) *(half8*)&SM[i] = z8;

    // ---- resident weights: whh0 (64 VGPR) + w1 (128 VGPR) ----
    half8 whh0[4][4];
    half8 w1[4][8];
    float bias1[4];
#pragma unroll
    for (int tI = 0; tI < 4; ++tI) {
        int g = tI * HD + wv * 16 + nn;
        bias1[tI] = bih1[g] + bhh1[g];
#pragma unroll
        for (int kk = 0; kk < 4; ++kk) {
            whh0[tI][kk] = ldw8(Whh0 + g * HD + kk * 32 + qd * 8);
            w1[tI][kk]     = ldw8(Wih1 + g * HD + kk * 32 + qd * 8);
            w1[tI][4 + kk] = ldw8(Whh1 + g * HD + kk * 32 + qd * 8);
        }
    }

    // ---- wih0 frag table into LDS (bias0 folded into K-row 24 via x col24=1.0) ----
    for (int e = tid; e < 2048; e += NTH) {
        int tI2 = e >> 9, wv2 = (e >> 6) & 7, ln2 = e & 63;
        int qd2 = ln2 >> 4, nn2 = ln2 & 15;
        int g = tI2 * HD + wv2 * 16 + nn2;
        half8 f = z8;
        if (qd2 < 3) f = ldw8(Wih0 + g * NIN + qd2 * 8);
        else         f[0] = (_Float16)(bih0[g] + bhh0[g]);   // K-row 24
        *(half8*)&SM[WIH0_OFF + e * 8] = f;
    }

    __syncthreads();   // zero-init + wih0 table visible

    // ---- stage x chunk 0 (steps 0..3) into buf 0 ----
    if (tid < XCH * BT * 7) {
        int ti = tid / 112, r = tid % 112, b = r / 7, q = r % 7;
        half4v h;
        if (q < 6) {
            float4 v = *(const float4*)(x + (size_t)(b0 + b) * (TSTEPS * NIN) + ti * NIN + q * 4);
            h[0] = (_Float16)v.x; h[1] = (_Float16)v.y; h[2] = (_Float16)v.z; h[3] = (_Float16)v.w;
        } else {
            h[0] = (_Float16)1.f; h[1] = 0; h[2] = 0; h[3] = 0;   // col 24 = 1.0 (bias hook)
        }
        *(half4v*)&SM[XB_OFF + ti * XTS + b * XS + q * 4] = h;
    }

    float cs0[4] = {0.f, 0.f, 0.f, 0.f};
    float cs1[4] = {0.f, 0.f, 0.f, 0.f};

    // ====== fused loop: iteration t = L0 step t + L1 step t-1 ======
#pragma unroll 1
    for (int t = 0; t <= TSTEPS; ++t) {
        __syncthreads();

        // stage x chunk t/XCH + 1 (for steps t+4..t+7)
        if (t < TSTEPS && (t & (XCH - 1)) == 0 && t + XCH < TSTEPS) {
            const int c = (t >> 2) + 1, buf = c & 1;
            if (tid < XCH * BT * 7) {
                int ti = tid / 112, r = tid % 112, b = r / 7, q = r % 7;
                half4v h;
                if (q < 6) {
                    float4 v = *(const float4*)(x + (size_t)(b0 + b) * (TSTEPS * NIN)
                                                  + (size_t)(c * XCH + ti) * NIN + q * 4);
                    h[0] = (_Float16)v.x; h[1] = (_Float16)v.y;
                    h[2] = (_Float16)v.z; h[3] = (_Float16)v.w;
                } else {
                    h[0] = (_Float16)1.f; h[1] = 0; h[2] = 0; h[3] = 0;
                }
                *(half4v*)&SM[XB_OFF + buf * XBUF + ti * XTS + b * XS + q * 4] = h;
            }
        }

        // -------- layer 0, step t --------
        if (t < TSTEPS) {
            const half8 ax = *(const half8*)&SM[XB_OFF + ((t >> 2) & 1) * XBUF
                                                + (t & (XCH - 1)) * XTS + nn * XS + qd * 8];
            floatx4 acc[4];
#pragma unroll
            for (int tI = 0; tI < 4; ++tI) {
                const half8 wf = *(const half8*)&SM[WIH0_OFF + ((tI * 8 + wv) * 64 + ln) * 8];
                floatx4 a = {0.f, 0.f, 0.f, 0.f};
                acc[tI] = __builtin_amdgcn_mfma_f32_16x16x32_f16(ax, wf, a, 0, 0, 0);
            }
            const int rp = (t & 1) ^ 1;      // h1_{t-1} slot
            half8 ah[4];
#pragma unroll
            for (int kk = 0; kk < 4; ++kk)
                ah[kk] = *(const half8*)&SM[H1_OFF + rp * SLOT + nn * RS + kk * 32 + qd * 8];
#pragma unroll
            for (int tI = 0; tI < 4; ++tI) {
#pragma unroll
                for (int kk = 0; kk < 4; ++kk)
                    acc[tI] = __builtin_amdgcn_mfma_f32_16x16x32_f16(ah[kk], whh0[tI][kk], acc[tI], 0, 0, 0);
            }
            const int wp = t & 1;            // h1_t slot
#pragma unroll
            for (int r = 0; r < 4; ++r) {
                float iv = sigf(acc[0][r]);
                float fv = sigf(acc[1][r]);
                float gv = tanh_f(acc[2][r]);
                float ov = sigf(acc[3][r]);
                float cn = fv * cs0[r] + iv * gv;
                cs0[r] = cn;
                float hv = ov * tanh_f(cn);
                SM[H1_OFF + wp * SLOT + (qd * 4 + r) * RS + jc] = (_Float16)hv;
            }
        }

        // -------- layer 1, step t-1 --------
        if (t >= 1) {
            const int rp = (t & 1) ^ 1;      // h1_{t-1} slot (and h2_{t-2} is slot t&1)
            floatx4 acc[4];
#pragma unroll
            for (int tI = 0; tI < 4; ++tI) {
                floatx4 a = {bias1[tI], bias1[tI], bias1[tI], bias1[tI]};
                acc[tI] = a;
            }
            half8 a1[4];
#pragma unroll
            for (int kk = 0; kk < 4; ++kk)
                a1[kk] = *(const half8*)&SM[H1_OFF + rp * SLOT + nn * RS + kk * 32 + qd * 8];
#pragma unroll
            for (int tI = 0; tI < 4; ++tI) {
#pragma unroll
                for (int kk = 0; kk < 4; ++kk)
                    acc[tI] = __builtin_amdgcn_mfma_f32_16x16x32_f16(a1[kk], w1[tI][kk], acc[tI], 0, 0, 0);
            }
            half8 a2[4];
#pragma unroll
            for (int kk = 0; kk < 4; ++kk)
                a2[kk] = *(const half8*)&SM[H2_OFF + (t & 1) * SLOT + nn * RS + kk * 32 + qd * 8];
#pragma unroll
            for (int tI = 0; tI < 4; ++tI) {
#pragma unroll
                for (int kk = 0; kk < 4; ++kk)
                    acc[tI] = __builtin_amdgcn_mfma_f32_16x16x32_f16(a2[kk], w1[tI][4 + kk], acc[tI], 0, 0, 0);
            }
            const int wp = (t & 1) ^ 1;      // h2_{t-1} slot
#pragma unroll
            for (int r = 0; r < 4; ++r) {
                float iv = sigf(acc[0][r]);
                float fv = sigf(acc[1][r]);
                float gv = tanh_f(acc[2][r]);
                float ov = sigf(acc[3][r]);
                float cn = fv * cs1[r] + iv * gv;
                cs1[r] = cn;
                float hv = ov * tanh_f(cn);
                SM[H2_OFF + wp * SLOT + (qd * 4 + r) * RS + jc] = (_Float16)hv;
            }
        }
    }
    __syncthreads();

    // ====== FC head: h2_127 is in H2 slot 1 ======
    {
        int b = tid >> 5, sub = tid & 31;
        const _Float16* hp = &SM[H2_OFF + SLOT + b * RS + sub * 4];
        const float4 wv4 = *(const float4*)(Wfc + sub * 4);
        float s = (float)hp[0] * wv4.x + (float)hp[1] * wv4.y
                + (float)hp[2] * wv4.z + (float)hp[3] * wv4.w;
        s += __shfl_down(s, 16, 32);
        s += __shfl_down(s, 8, 32);
        s += __shfl_down(s, 4, 32);
        s += __shfl_down(s, 2, 32);
        s += __shfl_down(s, 1, 32);
        if (sub == 0) out[b0 + b] = s + bfc[0];
    }
}

extern "C" void kernel_launch(void* const* d_in, const int* in_sizes, int n_in,
                              void* d_out, int out_size, void* d_ws, size_t ws_size,
                              hipStream_t stream) {
    const float* x    = (const float*)d_in[0];
    const float* Wih0 = (const float*)d_in[1];
    const float* Whh0 = (const float*)d_in[2];
    const float* bih0 = (const float*)d_in[3];
    const float* bhh0 = (const float*)d_in[4];
    const float* Wih1 = (const float*)d_in[5];
    const float* Whh1 = (const float*)d_in[6];
    const float* bih1 = (const float*)d_in[7];
    const float* bhh1 = (const float*)d_in[8];
    const float* Wfc  = (const float*)d_in[9];
    const float* bfc  = (const float*)d_in[10];
    float* out = (float*)d_out;

    lstm2_il<<<dim3(NBLK), dim3(NTH), 0, stream>>>(
        x, Wih0, Whh0, bih0, bhh0, Wih1, Whh1, bih1, bhh1, Wfc, bfc, out);
}